// Round 9
// baseline (132.831 us; speedup 1.0000x reference)
//
#include <hip/hip_runtime.h>

#define BS 16
#define V  2048
#define C  512
#define PN 512
#define K  16
#define NT 256

typedef unsigned long long u64;
typedef unsigned int u32;

// --- wave64 min over u32, VALU-only (v_min_u32 + DPP), result uniform ---
template<int CTRL>
__device__ __forceinline__ u32 min_dpp_u32(u32 x) {
    const u32 n = (u32)__builtin_amdgcn_update_dpp((int)x, (int)x, CTRL, 0xF, 0xF, false);
    return n < x ? n : x;   // bound_ctrl=false: edge lanes keep own value; min idempotent
}
__device__ __forceinline__ u32 wave_min_u32(u32 x) {
    x = min_dpp_u32<0x111>(x);  // row_shr:1
    x = min_dpp_u32<0x112>(x);  // row_shr:2
    x = min_dpp_u32<0x114>(x);  // row_shr:4
    x = min_dpp_u32<0x118>(x);  // row_shr:8
    x = min_dpp_u32<0x142>(x);  // row_bcast:15
    x = min_dpp_u32<0x143>(x);  // row_bcast:31 -> lane63 = wave min
    return (u32)__builtin_amdgcn_readlane((int)x, 63);
}
// u64 max with DPP (row_ror rotate-reduce; rotation has no invalid lanes)
template<int CTRL>
__device__ __forceinline__ u64 max_dpp_u64(u64 x) {
    const int lo = (int)(u32)x, hi = (int)(u32)(x >> 32);
    const int plo = __builtin_amdgcn_update_dpp(lo, lo, CTRL, 0xF, 0xF, false);
    const int phi = __builtin_amdgcn_update_dpp(hi, hi, CTRL, 0xF, 0xF, false);
    const u64 p = ((u64)(u32)phi << 32) | (u32)plo;
    return p > x ? p : x;
}
// u64 cross-lane fetch via ds_swizzle (BitMode: xor<<10 | and=0x1F); 32-lane groups
template<int OFS>
__device__ __forceinline__ u64 swz_u64(u64 x) {
    const int lo = __builtin_amdgcn_ds_swizzle((int)(u32)x, OFS);
    const int hi = __builtin_amdgcn_ds_swizzle((int)(u32)(x >> 32), OFS);
    return ((u64)(u32)hi << 32) | (u32)lo;
}
// one bitonic-merge stage at distance D (partner = lane XOR D), ascending
template<int D, int OFS>
__device__ __forceinline__ u64 bitonic_stage(u64 x, int ll) {
    const u64 p = swz_u64<OFS>(x);
    const bool keepmin = ((ll & D) == 0);
    const bool pl = (p < x);
    const bool takep = keepmin ? pl : !pl;   // keys unique -> p!=x where it matters
    return takep ? p : x;
}
__device__ __forceinline__ int mbcnt64(u64 m) {
    return __builtin_amdgcn_mbcnt_hi((u32)(m >> 32),
           __builtin_amdgcn_mbcnt_lo((u32)m, 0));
}

// compare-exchange on u64 sort keys (register-resident, literal indices)
#define CE(i, j) { const bool p_ = sk[j] < sk[i]; const u64 a_ = p_ ? sk[j] : sk[i]; \
                   const u64 b_ = p_ ? sk[i] : sk[j]; sk[i] = a_; sk[j] = b_; }

// one exact pop of the wave's lex-min (dist,idx) into wlist[slot].
// No hidden-dup ballot needed: wm = min over lane frontiers; per-lane
// sortedness => any lane holding a wm-valued element has d0 == wm, so
// cnt==1 => winner's d0 is the global lex-min; cnt>1 => min-idx over the
// tied frontiers is the global lex-min (uniform branch, ~never taken).
#define POP_ONE(SLOT)                                                          \
    {                                                                          \
        const u32 wm = wave_min_u32(d0);                                       \
        const bool pred = (d0 == wm);                                          \
        const u64 mask = __ballot(pred);                                       \
        bool w_;                                                               \
        if (__popcll(mask) == 1) {                                             \
            w_ = pred;                                                         \
        } else {                                                               \
            const u32 myidx = pred ? (wbase + ((perm & 15u) << 6) + (u32)lane) \
                                   : 0xFFFFFFFFu;                              \
            const u32 wi = wave_min_u32(myidx);                                \
            w_ = pred && (myidx == wi);                                        \
        }                                                                      \
        if (w_) {                                                              \
            const u32 idx = wbase + ((perm & 15u) << 6) + (u32)lane;           \
            wlist[wid * 16 + (SLOT)] = ((u64)d0 << 32) | idx;                  \
        }                                                                      \
        d0 = w_ ? d1 : d0; d1 = w_ ? d2 : d1; d2 = w_ ? d3 : d2;               \
        d3 = w_ ? d4 : d3; d4 = w_ ? d5 : d4; d5 = w_ ? d6 : d5;               \
        d6 = w_ ? d7 : d6; d7 = w_ ? 0xFFFFFFFFu : d7;                         \
        perm = w_ ? (perm >> 4) : perm;                                        \
    }

__global__ __launch_bounds__(NT) void pool_knn_kernel(
    const float* __restrict__ vert,   // [BS, V, 3]
    const float* __restrict__ feat,   // [BS, V, C]
    const int*   __restrict__ sidx,   // [PN]
    float* __restrict__ out)          // [BS*PN*3] ++ [BS*PN*C]
{
    // XCD-aware swizzle (bijective: 8192 % 8 == 0): HW round-robins dispatch
    // index over 8 XCDs, so this gives each XCD a contiguous 1024-block chunk
    // = exactly 2 batches -> feat working set 8MB/XCD instead of 64MB.
    const int wk = ((blockIdx.x & 7) << 10) | (blockIdx.x >> 3);
    const int b = wk >> 9;
    const int s = wk & (PN - 1);
    const int t = threadIdx.x;
    const int wid = t >> 6;
    const int lane = t & 63;
    const u32 wbase = (u32)wid * 512u;

    __shared__ u64 wlist[64];          // 4 waves x up-to-16 offered keys
    __shared__ u64 sB16;
    __shared__ int nbr[K];
    __shared__ int flagw;              // resume bitmask (written by wave0)
    __shared__ int cntw[4];
    if (t < 4) cntw[t] = 8;

    const int q = sidx[s];
    const float* vb = vert + (size_t)b * (V * 3);
    const float qx = vb[q * 3 + 0];
    const float qy = vb[q * 3 + 1];
    const float qz = vb[q * 3 + 2];
    const float qq = qx * qx + qy * qy + qz * qz;

    // ---- Phase 1: 8 distances/thread; sort (dist, slot); keep u32 dists +
    //      nibble slot-permutation (idx = wbase + slot*64 + lane) ----
    u32 d0, d1, d2, d3, d4, d5, d6, d7, perm;
    {
        u64 sk[8];
        #pragma unroll
        for (int i = 0; i < 8; ++i) {
            const int m = (int)wbase + i * 64 + lane;
            const float mx = vb[m * 3 + 0];
            const float my = vb[m * 3 + 1];
            const float mz = vb[m * 3 + 2];
            const float qm = mx * mx + my * my + mz * mz;
            const float inner = qx * mx + qy * my + qz * mz;
            const float dist = (-2.0f * inner + qm) + qq;   // exact ref ordering
            u32 u = __float_as_uint(dist);
            u ^= (u & 0x80000000u) ? 0xFFFFFFFFu : 0x80000000u;  // monotone map
            if (m == q) u = 0xFFFFFFFFu;                          // exclude self
            sk[i] = ((u64)u << 32) | (u32)i;   // tie-break by slot == idx order
        }
        CE(0,1) CE(2,3) CE(4,5) CE(6,7)
        CE(0,2) CE(1,3) CE(4,6) CE(5,7)
        CE(1,2) CE(5,6) CE(0,4) CE(3,7)
        CE(1,5) CE(2,6)
        CE(1,4) CE(3,6)
        CE(2,4) CE(3,5)
        CE(3,4)
        d0 = (u32)(sk[0] >> 32); d1 = (u32)(sk[1] >> 32);
        d2 = (u32)(sk[2] >> 32); d3 = (u32)(sk[3] >> 32);
        d4 = (u32)(sk[4] >> 32); d5 = (u32)(sk[5] >> 32);
        d6 = (u32)(sk[6] >> 32); d7 = (u32)(sk[7] >> 32);
        perm = (u32)sk[0]        | ((u32)sk[1] << 4)  | ((u32)sk[2] << 8)  |
               ((u32)sk[3] << 12)| ((u32)sk[4] << 16) | ((u32)sk[5] << 20) |
               ((u32)sk[6] << 24)| ((u32)sk[7] << 28);
    }

    // ---- Phase 2a: exactly 8 lex-ordered pops per wave ----
    #pragma unroll
    for (int r = 0; r < 8; ++r) { POP_ONE(r) }
    __syncthreads();                       // barrier 1: wlist published

    // ---- Phase 2b (wave 0 only): bitonic merge of 4 sorted-8 runs ->
    //      top-16 set; B16 = max winner; resume bitmask; publish via LDS ----
    if (wid == 0) {
        u64 x;
        {
            const int w = lane >> 3;                               // run id
            const int rr = (w & 1) ? (7 - (lane & 7)) : (lane & 7);
            const int addr = (w & 3) * 16 + rr;
            const u64 ld = wlist[(lane < 32) ? addr : 0];
            x = (lane < 32) ? ld : ~0ULL;
            const int ll = lane & 15;
            x = bitonic_stage<8, 0x201F>(x, ll);   // xor 8
            x = bitonic_stage<4, 0x101F>(x, ll);   // xor 4
            x = bitonic_stage<2, 0x081F>(x, ll);   // xor 2
            x = bitonic_stage<1, 0x041F>(x, ll);   // xor 1
            const u64 p = swz_u64<0x7C1F>(x);      // xor 31: S_i <-> T_{15-i}
            x = (p < x) ? p : x;                   // lanes0-15: exact top-16 set
        }
        if (lane < 16) nbr[lane] = (int)(u32)x;    // optimistic publish
        u64 B16;
        {
            u64 bm = (lane < 16) ? x : 0ULL;
            bm = max_dpp_u64<0x121>(bm);  // row_ror:1
            bm = max_dpp_u64<0x122>(bm);  // row_ror:2
            bm = max_dpp_u64<0x124>(bm);  // row_ror:4
            bm = max_dpp_u64<0x128>(bm);  // row_ror:8
            const u32 blo = (u32)__builtin_amdgcn_readlane((int)(u32)bm, 0);
            const u32 bhi = (u32)__builtin_amdgcn_readlane((int)(u32)(bm >> 32), 0);
            B16 = ((u64)bhi << 32) | blo;
        }
        // wave w must resume iff its 8th offer < B16 (stale-B16 >= true g16)
        const u64 k8w = wlist[(lane & 3) * 16 + 7];
        const bool rp = (lane < 4) && (k8w < B16);
        const int resmask = (int)(__ballot(rp) & 0xFull);
        if (lane == 0) { flagw = resmask; sB16 = B16; }
    }
    __syncthreads();                           // barrier 2

    const int fl = flagw;
    if (fl != 0) {
        // ---- rare exact path: flagged waves pop until frontier key > B16
        //      (cap 16 total: no wave can contribute >16) ----
        const u64 B16v = sB16;
        if ((fl >> wid) & 1) {
            int r = 8;
            while (r < 16) {
                const u32 fm = wave_min_u32(d0);
                if (((u64)fm << 32) > B16v) break;   // unpopped all > B16 >= g16
                POP_ONE(r)
                ++r;
            }
            if (lane == 0) cntw[wid] = r;
        }
        __syncthreads();                       // barrier 3
        if (wid == 0) {
            // exact 16-pop set-merge over up-to-64 candidates (validity-masked)
            const int cv = cntw[lane >> 4];
            const u64 ck = ((lane & 15) < cv) ? wlist[lane] : ~0ULL;
            u32 cd = (u32)(ck >> 32);
            const u32 ci = (u32)ck;
            int r = 0;
            while (r < K) {
                const u32 wm = wave_min_u32(cd);
                const bool pred = (cd == wm);
                const u64 mask = __ballot(pred);
                const int cnt = (int)__popcll(mask);
                if (r + cnt <= K) {
                    if (pred) nbr[r + mbcnt64(mask)] = (int)ci;
                    cd = pred ? 0xFFFFFFFFu : cd;
                    r += cnt;
                } else {
                    const u32 mi = pred ? ci : 0xFFFFFFFFu;
                    const u32 wi = wave_min_u32(mi);
                    const bool w2 = pred && (ci == wi);
                    if (w2) nbr[r] = (int)ci;
                    cd = w2 ? 0xFFFFFFFFu : cd;
                    r += 1;
                }
            }
        }
        __syncthreads();                       // barrier 4
    }

    // ---- Phase 3: all waves read the 16 winners (uniform LDS broadcast ->
    //      SGPR row bases) and gather + channel-wise max ----
    int nidx[K];
    #pragma unroll
    for (int r = 0; r < K; ++r)
        nidx[r] = __builtin_amdgcn_readfirstlane(nbr[r]);

    const float* fb = feat + (size_t)b * (V * C);
    const int ch = t * 2;
    float m0 = -__builtin_inff(), m1 = -__builtin_inff();
    #pragma unroll
    for (int r = 0; r < K; ++r) {
        const float2 f = *reinterpret_cast<const float2*>(fb + (size_t)nidx[r] * C + ch);
        m0 = fmaxf(m0, f.x);
        m1 = fmaxf(m1, f.y);
    }
    float* o1 = out + (size_t)BS * PN * 3 + (size_t)(b * PN + s) * C + ch;
    o1[0] = m0;
    o1[1] = m1;

    if (t < 3) {
        out[(size_t)(b * PN + s) * 3 + t] = vb[q * 3 + t];
    }
}

extern "C" void kernel_launch(void* const* d_in, const int* in_sizes, int n_in,
                              void* d_out, int out_size, void* d_ws, size_t ws_size,
                              hipStream_t stream) {
    const float* vert = (const float*)d_in[0];
    const float* feat = (const float*)d_in[1];
    const int*   sidx = (const int*)d_in[2];
    float* out = (float*)d_out;

    pool_knn_kernel<<<BS * PN, NT, 0, stream>>>(vert, feat, sidx, out);
}

// Round 10
// 131.831 us; speedup vs baseline: 1.0076x; 1.0076x over previous
//
#include <hip/hip_runtime.h>

#define BS 16
#define V  2048
#define C  512
#define PN 512
#define K  16
#define NT 256

typedef unsigned long long u64;
typedef unsigned int u32;

// --- wave64 min over u32, VALU-only (v_min_u32 + DPP), result uniform ---
template<int CTRL>
__device__ __forceinline__ u32 min_dpp_u32(u32 x) {
    const u32 n = (u32)__builtin_amdgcn_update_dpp((int)x, (int)x, CTRL, 0xF, 0xF, false);
    return n < x ? n : x;   // bound_ctrl=false: edge lanes keep own value; min idempotent
}
__device__ __forceinline__ u32 wave_min_u32(u32 x) {
    x = min_dpp_u32<0x111>(x);  // row_shr:1
    x = min_dpp_u32<0x112>(x);  // row_shr:2
    x = min_dpp_u32<0x114>(x);  // row_shr:4
    x = min_dpp_u32<0x118>(x);  // row_shr:8
    x = min_dpp_u32<0x142>(x);  // row_bcast:15
    x = min_dpp_u32<0x143>(x);  // row_bcast:31 -> lane63 = wave min
    return (u32)__builtin_amdgcn_readlane((int)x, 63);
}
// u64 max with DPP (row_ror rotate-reduce; rotation has no invalid lanes)
template<int CTRL>
__device__ __forceinline__ u64 max_dpp_u64(u64 x) {
    const int lo = (int)(u32)x, hi = (int)(u32)(x >> 32);
    const int plo = __builtin_amdgcn_update_dpp(lo, lo, CTRL, 0xF, 0xF, false);
    const int phi = __builtin_amdgcn_update_dpp(hi, hi, CTRL, 0xF, 0xF, false);
    const u64 p = ((u64)(u32)phi << 32) | (u32)plo;
    return p > x ? p : x;
}
// u64 cross-lane fetch via ds_swizzle (BitMode: xor<<10 | and=0x1F); 32-lane groups
template<int OFS>
__device__ __forceinline__ u64 swz_u64(u64 x) {
    const int lo = __builtin_amdgcn_ds_swizzle((int)(u32)x, OFS);
    const int hi = __builtin_amdgcn_ds_swizzle((int)(u32)(x >> 32), OFS);
    return ((u64)(u32)hi << 32) | (u32)lo;
}
// one bitonic-merge stage at distance D (partner = lane XOR D), ascending
template<int D, int OFS>
__device__ __forceinline__ u64 bitonic_stage(u64 x, int ll) {
    const u64 p = swz_u64<OFS>(x);
    const bool keepmin = ((ll & D) == 0);
    const bool pl = (p < x);
    const bool takep = keepmin ? pl : !pl;   // keys unique -> p!=x where it matters
    return takep ? p : x;
}
__device__ __forceinline__ int mbcnt64(u64 m) {
    return __builtin_amdgcn_mbcnt_hi((u32)(m >> 32),
           __builtin_amdgcn_mbcnt_lo((u32)m, 0));
}

// compare-exchange on u64 sort keys (register-resident, literal indices)
#define CE(i, j) { const bool p_ = sk[j] < sk[i]; const u64 a_ = p_ ? sk[j] : sk[i]; \
                   const u64 b_ = p_ ? sk[i] : sk[j]; sk[i] = a_; sk[j] = b_; }

// distances+sort for one query -> named u32 dists + nibble slot perm
#define BUILD_SORT(QX,QY,QZ,QQ,QIDX,D0,D1,D2,D3,D4,D5,D6,D7,PERM)              \
    {                                                                          \
        u64 sk[8];                                                             \
        _Pragma("unroll")                                                      \
        for (int i = 0; i < 8; ++i) {                                          \
            const int m = (int)wbase + i * 64 + lane;                          \
            const float inner = (QX)*px[i] + (QY)*py[i] + (QZ)*pz[i];          \
            const float dist = (-2.0f * inner + pq[i]) + (QQ);                 \
            u32 u = __float_as_uint(dist);                                     \
            u ^= (u & 0x80000000u) ? 0xFFFFFFFFu : 0x80000000u;                \
            if (m == (QIDX)) u = 0xFFFFFFFFu;                                  \
            sk[i] = ((u64)u << 32) | (u32)i;                                   \
        }                                                                      \
        CE(0,1) CE(2,3) CE(4,5) CE(6,7)                                        \
        CE(0,2) CE(1,3) CE(4,6) CE(5,7)                                        \
        CE(1,2) CE(5,6) CE(0,4) CE(3,7)                                        \
        CE(1,5) CE(2,6)                                                        \
        CE(1,4) CE(3,6)                                                        \
        CE(2,4) CE(3,5)                                                        \
        CE(3,4)                                                                \
        D0 = (u32)(sk[0] >> 32); D1 = (u32)(sk[1] >> 32);                      \
        D2 = (u32)(sk[2] >> 32); D3 = (u32)(sk[3] >> 32);                      \
        D4 = (u32)(sk[4] >> 32); D5 = (u32)(sk[5] >> 32);                      \
        D6 = (u32)(sk[6] >> 32); D7 = (u32)(sk[7] >> 32);                      \
        PERM = (u32)sk[0]        | ((u32)sk[1] << 4)  | ((u32)sk[2] << 8)  |   \
               ((u32)sk[3] << 12)| ((u32)sk[4] << 16) | ((u32)sk[5] << 20) |   \
               ((u32)sk[6] << 24)| ((u32)sk[7] << 28);                         \
    }

// one exact pop of the wave's lex-min (dist,idx) into WL[SLOT] (round-9 proven)
#define POP_ONE(D0,D1,D2,D3,D4,D5,D6,D7,PERM,WL,SLOT)                          \
    {                                                                          \
        const u32 wm = wave_min_u32(D0);                                       \
        const bool pred = (D0 == wm);                                          \
        const u64 mask = __ballot(pred);                                       \
        bool w_;                                                               \
        if (__popcll(mask) == 1) {                                             \
            w_ = pred;                                                         \
        } else {                                                               \
            const u32 myidx = pred ? (wbase + (((PERM) & 15u) << 6) + (u32)lane) \
                                   : 0xFFFFFFFFu;                              \
            const u32 wi = wave_min_u32(myidx);                                \
            w_ = pred && (myidx == wi);                                        \
        }                                                                      \
        if (w_) {                                                               \
            const u32 idx = wbase + (((PERM) & 15u) << 6) + (u32)lane;         \
            (WL)[SLOT] = ((u64)(D0) << 32) | idx;                              \
        }                                                                      \
        D0 = w_ ? D1 : D0; D1 = w_ ? D2 : D1; D2 = w_ ? D3 : D2;               \
        D3 = w_ ? D4 : D3; D4 = w_ ? D5 : D4; D5 = w_ ? D6 : D5;               \
        D6 = w_ ? D7 : D6; D7 = w_ ? 0xFFFFFFFFu : D7;                         \
        PERM = w_ ? ((PERM) >> 4) : (PERM);                                    \
    }

// bitonic merge of 4 sorted-8 runs -> top-16 set + B16 + resume mask
#define MERGE8(WLQ,NBRQ,SB16Q,FLAGQ)                                           \
    {                                                                          \
        u64 x;                                                                 \
        {   const int w = lane >> 3;                                           \
            const int rr = (w & 1) ? (7 - (lane & 7)) : (lane & 7);            \
            const int addr = (w & 3) * 16 + rr;                                \
            const u64 ld = (WLQ)[(lane < 32) ? addr : 0];                      \
            x = (lane < 32) ? ld : ~0ULL;                                      \
            const int ll = lane & 15;                                          \
            x = bitonic_stage<8, 0x201F>(x, ll);                               \
            x = bitonic_stage<4, 0x101F>(x, ll);                               \
            x = bitonic_stage<2, 0x081F>(x, ll);                               \
            x = bitonic_stage<1, 0x041F>(x, ll);                               \
            const u64 p = swz_u64<0x7C1F>(x);                                  \
            x = (p < x) ? p : x; }                                             \
        if (lane < 16) (NBRQ)[lane] = (int)(u32)x;                             \
        u64 B16;                                                               \
        {   u64 bm = (lane < 16) ? x : 0ULL;                                   \
            bm = max_dpp_u64<0x121>(bm);                                       \
            bm = max_dpp_u64<0x122>(bm);                                       \
            bm = max_dpp_u64<0x124>(bm);                                       \
            bm = max_dpp_u64<0x128>(bm);                                       \
            const u32 blo = (u32)__builtin_amdgcn_readlane((int)(u32)bm, 0);   \
            const u32 bhi = (u32)__builtin_amdgcn_readlane((int)(u32)(bm >> 32), 0); \
            B16 = ((u64)bhi << 32) | blo; }                                    \
        const u64 k8w = (WLQ)[(lane & 3) * 16 + 7];                            \
        const bool rp = (lane < 4) && (k8w < B16);                             \
        const int resmask = (int)(__ballot(rp) & 0xFull);                      \
        if (lane == 0) { FLAGQ = resmask; SB16Q = B16; }                       \
    }

// exact 16-pop set-merge over up-to-64 candidates (validity-masked, rare path)
#define RMERGE(WLQ,NBRQ,CV)                                                    \
    {   const int cv = (CV)[lane >> 4];                                        \
        const u64 ck = ((lane & 15) < cv) ? (WLQ)[lane] : ~0ULL;               \
        u32 cd = (u32)(ck >> 32);                                              \
        const u32 ci = (u32)ck;                                                \
        int r = 0;                                                             \
        while (r < K) {                                                        \
            const u32 wm = wave_min_u32(cd);                                   \
            const bool pred = (cd == wm);                                      \
            const u64 mask = __ballot(pred);                                   \
            const int cnt = (int)__popcll(mask);                               \
            if (r + cnt <= K) {                                                \
                if (pred) (NBRQ)[r + mbcnt64(mask)] = (int)ci;                 \
                cd = pred ? 0xFFFFFFFFu : cd;                                  \
                r += cnt;                                                      \
            } else {                                                           \
                const u32 mi = pred ? ci : 0xFFFFFFFFu;                        \
                const u32 wi = wave_min_u32(mi);                               \
                const bool w2 = pred && (ci == wi);                            \
                if (w2) (NBRQ)[r] = (int)ci;                                   \
                cd = w2 ? 0xFFFFFFFFu : cd;                                    \
                r += 1;                                                        \
            }                                                                  \
        }                                                                      \
    }

// resume pops for one query until frontier > B16 (exact; cap 16)
#define RESUME(D0,D1,D2,D3,D4,D5,D6,D7,PERM,WL,BV,CVSLOT)                      \
    {   int r = 8;                                                             \
        while (r < 16) {                                                       \
            const u32 fm = wave_min_u32(D0);                                   \
            if (((u64)fm << 32) > (BV)) break;                                 \
            POP_ONE(D0,D1,D2,D3,D4,D5,D6,D7,PERM,WL,r)                         \
            ++r;                                                               \
        }                                                                      \
        if (lane == 0) (CVSLOT) = r;                                           \
    }

__global__ __launch_bounds__(NT) void pool_knn_kernel(
    const float* __restrict__ vert,   // [BS, V, 3]
    const float* __restrict__ feat,   // [BS, V, C]
    const int*   __restrict__ sidx,   // [PN]
    float* __restrict__ out)          // [BS*PN*3] ++ [BS*PN*C]
{
    // 2 queries/block -> 4096 blocks. XCD swizzle (bijective, 4096%8==0):
    // each XCD gets a contiguous 512-block chunk = 2 batches (8MB feat in L2).
    const int wk = ((blockIdx.x & 7) << 9) | (blockIdx.x >> 3);
    const int b  = wk >> 8;
    const int sg = wk & 255;
    const int sA = sg * 2, sB = sA + 1;
    const int t = threadIdx.x;
    const int wid = t >> 6;
    const int lane = t & 63;
    const u32 wbase = (u32)wid * 512u;

    __shared__ u64 wlist[128];         // [query][wave*16 + slot]
    __shared__ u64 sB16[2];
    __shared__ int nbr[2][K];
    __shared__ int flagA, flagB;
    __shared__ int cntw[2][4];
    if (t < 4) { cntw[0][t] = 8; cntw[1][t] = 8; }

    const int qA = sidx[sA];
    const int qB = sidx[sB];
    const float* vb = vert + (size_t)b * (V * 3);
    const float qxA = vb[qA * 3 + 0], qyA = vb[qA * 3 + 1], qzA = vb[qA * 3 + 2];
    const float qxB = vb[qB * 3 + 0], qyB = vb[qB * 3 + 1], qzB = vb[qB * 3 + 2];
    const float qqA = qxA * qxA + qyA * qyA + qzA * qzA;
    const float qqB = qxB * qxB + qyB * qyB + qzB * qzB;

    // ---- Phase 1 (shared): load 8 points/thread once; per-point norms ----
    float px[8], py[8], pz[8], pq[8];
    #pragma unroll
    for (int i = 0; i < 8; ++i) {
        const int m = (int)wbase + i * 64 + lane;
        px[i] = vb[m * 3 + 0];
        py[i] = vb[m * 3 + 1];
        pz[i] = vb[m * 3 + 2];
        pq[i] = px[i] * px[i] + py[i] * py[i] + pz[i] * pz[i];
    }

    u32 a0, a1, a2, a3, a4, a5, a6, a7, aperm;
    u32 b0, b1, b2, b3, b4, b5, b6, b7, bperm;
    BUILD_SORT(qxA, qyA, qzA, qqA, qA, a0,a1,a2,a3,a4,a5,a6,a7, aperm)
    BUILD_SORT(qxB, qyB, qzB, qqB, qB, b0,b1,b2,b3,b4,b5,b6,b7, bperm)

    // ---- Phase 2a: 8 lex-ordered pops per wave per query; the two queries'
    //      DPP chains are independent -> they interleave in the issue slots ----
    u64* const wlA = &wlist[wid * 16];
    u64* const wlB = &wlist[64 + wid * 16];
    #pragma unroll
    for (int r = 0; r < 8; ++r) {
        POP_ONE(a0,a1,a2,a3,a4,a5,a6,a7, aperm, wlA, r)
        POP_ONE(b0,b1,b2,b3,b4,b5,b6,b7, bperm, wlB, r)
    }
    __syncthreads();                       // barrier 1: wlist published

    // ---- Phase 2b: wave0 merges query A, wave1 merges query B (parallel) ----
    if (wid == 0)      { MERGE8(&wlist[0],  nbr[0], sB16[0], flagA) }
    else if (wid == 1) { MERGE8(&wlist[64], nbr[1], sB16[1], flagB) }
    __syncthreads();                       // barrier 2

    const int flA = flagA, flB = flagB;
    if ((flA | flB) != 0) {
        // ---- rare exact path: flagged waves resume the flagged query ----
        if ((flA >> wid) & 1) {
            const u64 Bv = sB16[0];
            RESUME(a0,a1,a2,a3,a4,a5,a6,a7, aperm, wlA, Bv, cntw[0][wid])
        }
        if ((flB >> wid) & 1) {
            const u64 Bv = sB16[1];
            RESUME(b0,b1,b2,b3,b4,b5,b6,b7, bperm, wlB, Bv, cntw[1][wid])
        }
        __syncthreads();                   // barrier 3
        if (wid == 0 && flA) { RMERGE(&wlist[0],  nbr[0], cntw[0]) }
        if (wid == 1 && flB) { RMERGE(&wlist[64], nbr[1], cntw[1]) }
        __syncthreads();                   // barrier 4
    }

    // ---- Phase 3: broadcast winners (SGPR bases), gather both queries ----
    int nA[K], nB[K];
    #pragma unroll
    for (int r = 0; r < K; ++r) {
        nA[r] = __builtin_amdgcn_readfirstlane(nbr[0][r]);
        nB[r] = __builtin_amdgcn_readfirstlane(nbr[1][r]);
    }

    const float* fb = feat + (size_t)b * (V * C);
    const int ch = t * 2;
    float mA0 = -__builtin_inff(), mA1 = -__builtin_inff();
    float mB0 = -__builtin_inff(), mB1 = -__builtin_inff();
    #pragma unroll
    for (int r = 0; r < K; ++r) {
        const float2 fA = *reinterpret_cast<const float2*>(fb + (size_t)nA[r] * C + ch);
        const float2 fB = *reinterpret_cast<const float2*>(fb + (size_t)nB[r] * C + ch);
        mA0 = fmaxf(mA0, fA.x); mA1 = fmaxf(mA1, fA.y);
        mB0 = fmaxf(mB0, fB.x); mB1 = fmaxf(mB1, fB.y);
    }
    float* oA = out + (size_t)BS * PN * 3 + (size_t)(b * PN + sA) * C + ch;
    oA[0] = mA0; oA[1] = mA1;
    float* oB = oA + C;
    oB[0] = mB0; oB[1] = mB1;

    if (t < 3) {
        out[(size_t)(b * PN + sA) * 3 + t] = vb[qA * 3 + t];
    } else if (t < 6) {
        out[(size_t)(b * PN + sB) * 3 + (t - 3)] = vb[qB * 3 + (t - 3)];
    }
}

extern "C" void kernel_launch(void* const* d_in, const int* in_sizes, int n_in,
                              void* d_out, int out_size, void* d_ws, size_t ws_size,
                              hipStream_t stream) {
    const float* vert = (const float*)d_in[0];
    const float* feat = (const float*)d_in[1];
    const int*   sidx = (const int*)d_in[2];
    float* out = (float*)d_out;

    pool_knn_kernel<<<(BS * PN) / 2, NT, 0, stream>>>(vert, feat, sidx, out);
}